// Round 4
// baseline (360.070 us; speedup 1.0000x reference)
//
#include <hip/hip_runtime.h>
#include <cstdint>
#include <cstddef>

// ---- problem constants ----
#define B_    4
#define S_    2048
#define D_    1024
#define H_    16
#define HD_   64
#define M_    8192      // B_*S_
#define NQKV  3072

typedef __bf16 bf16;
typedef __bf16 bf16x4 __attribute__((ext_vector_type(4)));
typedef __bf16 bf16x8 __attribute__((ext_vector_type(8)));
typedef float  f32x4  __attribute__((ext_vector_type(4)));
typedef float  f32x16 __attribute__((ext_vector_type(16)));
typedef unsigned short u16x4 __attribute__((ext_vector_type(4)));
typedef uint32_t u32x4 __attribute__((ext_vector_type(4)));

// async global->LDS, 16B per lane. LDS dest is wave-uniform base + lane*16.
__device__ __forceinline__ void gl2lds16(const void* g, void* l) {
  __builtin_amdgcn_global_load_lds(
      (__attribute__((address_space(1))) void*)(uintptr_t)g,
      (__attribute__((address_space(3))) void*)l, 16, 0, 0);
}

__device__ __forceinline__ uint32_t pkbf16(float a, float b) {
  union { bf16 h[2]; uint32_t u; } z;
  z.h[0] = (bf16)a; z.h[1] = (bf16)b;
  return z.u;
}

// ---- prep: fp32 -> bf16 cast (x) ----
__global__ __launch_bounds__(256) void cast_f32_bf16(const float* __restrict__ in,
                                                     bf16* __restrict__ out, int n4) {
  int i = blockIdx.x * 256 + threadIdx.x;
  if (i >= n4) return;
  float4 v = ((const float4*)in)[i];
  bf16x4 o;
  o[0] = (bf16)v.x; o[1] = (bf16)v.y; o[2] = (bf16)v.z; o[3] = (bf16)v.w;
  ((bf16x4*)out)[i] = o;
}

// ---- prep: transpose + cast: in [R,C] fp32 -> out [C,R] bf16 ----
__global__ __launch_bounds__(256) void transpose_cast(const float* __restrict__ in,
                                                      bf16* __restrict__ out, int R, int C) {
  __shared__ float tile[32][33];
  int bx = blockIdx.x * 32, by = blockIdx.y * 32;
  int tx = threadIdx.x, ty = threadIdx.y;
#pragma unroll
  for (int i = 0; i < 32; i += 8)
    tile[ty + i][tx] = in[(size_t)(by + ty + i) * C + bx + tx];
  __syncthreads();
#pragma unroll
  for (int i = 0; i < 32; i += 8)
    out[(size_t)(bx + ty + i) * R + by + tx] = (bf16)tile[tx][ty + i];
}

// ---- m97-style GEMM: C[M,N] = A[M,K] * Bt[N,K]^T + bias ----
template <bool OUT_BF16>
__global__ __launch_bounds__(256) void gemm_bt(const bf16* __restrict__ A,
                                               const bf16* __restrict__ Bt,
                                               const float* __restrict__ bias,
                                               void* __restrict__ Cptr,
                                               int M, int N, int K) {
  __shared__ __align__(16) bf16 As[128 * 64];
  __shared__ __align__(16) bf16 Bs[128 * 64];
  const int tid  = threadIdx.x;
  const int lane = tid & 63, w = tid >> 6;
  const int lo   = lane & 15, quad = lane >> 4;
  const int bm = blockIdx.y * 128, bn = blockIdx.x * 128;
  const int wm = (w >> 1) * 64,    wn = (w & 1) * 64;

  f32x4 acc[4][4];
  const f32x4 zero = {0.f, 0.f, 0.f, 0.f};
#pragma unroll
  for (int i = 0; i < 4; ++i)
#pragma unroll
    for (int j = 0; j < 4; ++j) acc[i][j] = zero;

  for (int k0 = 0; k0 < K; k0 += 64) {
#pragma unroll
    for (int c = 0; c < 4; ++c) {
      int seg = c * 4 + w;
      int idx = seg * 512 + lane * 8;
      int row = idx >> 6, col = idx & 63;
      gl2lds16(A  + (size_t)(bm + row) * K + k0 + col, As + seg * 512);
      gl2lds16(Bt + (size_t)(bn + row) * K + k0 + col, Bs + seg * 512);
    }
    __syncthreads();
#pragma unroll
    for (int ks = 0; ks < 2; ++ks) {
      bf16x8 av[4], bv[4];
#pragma unroll
      for (int i = 0; i < 4; ++i)
        av[i] = *(const bf16x8*)&As[(wm + i * 16 + lo) * 64 + ks * 32 + quad * 8];
#pragma unroll
      for (int j = 0; j < 4; ++j)
        bv[j] = *(const bf16x8*)&Bs[(wn + j * 16 + lo) * 64 + ks * 32 + quad * 8];
#pragma unroll
      for (int i = 0; i < 4; ++i)
#pragma unroll
        for (int j = 0; j < 4; ++j)
          acc[i][j] = __builtin_amdgcn_mfma_f32_16x16x32_bf16(av[i], bv[j], acc[i][j], 0, 0, 0);
    }
    __syncthreads();
  }
#pragma unroll
  for (int j = 0; j < 4; ++j) {
    int cg = bn + wn + j * 16 + lo;
    float bsv = bias[cg];
#pragma unroll
    for (int i = 0; i < 4; ++i) {
      int rg = bm + wm + i * 16 + quad * 4;
#pragma unroll
      for (int r = 0; r < 4; ++r) {
        float v = acc[i][j][r] + bsv;
        if (OUT_BF16) ((bf16*)Cptr)[(size_t)(rg + r) * N + cg] = (bf16)v;
        else          ((float*)Cptr)[(size_t)(rg + r) * N + cg] = v;
      }
    }
  }
}

// ---- flash attention v4 ----
// 128 q/block, 4 waves x 32 q, 32x32x16 MFMA. S^T = K.Q^T, O^T = Vt.P (q = C-col =
// lane&31 -> softmax in-lane). Fixed exponent offset (p = 2^(s*c2-16), exact pow2
// scaling cancels in O/lsum). K fragments DIRECT from global (no LDS round-trip;
// per-lane 16B contiguous, L1/L2-served, XCD swizzle keeps tiles hot). V through
// double-buffered XOR-swizzled LDS (needs transpose). P C-layout -> B-frag via
// 2x shfl_xor(32) per MFMA. Epilogue: O -> LDS (swizzled) -> coalesced 16B stores.
__global__ __launch_bounds__(256, 4) void flash_attn(const bf16* __restrict__ qkv,
                                                     bf16* __restrict__ out) {
  __shared__ __align__(16) bf16 Vs[2][64 * 64];   // 16 KB; reused as O-stage in epilogue

  const int tid  = threadIdx.x;
  const int lane = tid & 63, wq = tid >> 6;
  const int l31  = lane & 31;
  const int e    = lane >> 5;           // hi1
  const int hi8  = e * 8, hi4 = e * 4;

  const int bid = blockIdx.x;
  const int qb  = bid >> 6;             // 0..15
  const int bh  = bid & 63;
  const int h   = bh & 15;
  const int b   = bh >> 4;
  const int q0  = qb * 128;
  const size_t rowb = (size_t)b * S_;
  const bf16* qbase = qkv + rowb * NQKV + h * HD_;
  const bf16* kbase = qbase + D_;
  const bf16* vbase = qbase + 2 * D_;

  // ---- Q fragments straight from global (loop-invariant) ----
  bf16x8 qf[4];
  {
    const bf16* qrow = qbase + (size_t)(q0 + wq * 32 + l31) * NQKV;
#pragma unroll
    for (int c = 0; c < 4; ++c)
      qf[c] = *(const bf16x8*)(qrow + c * 16 + hi8);
  }

  // ---- per-lane K fragment pointers (advance by 64*NQKV per tile) ----
  const bf16* kp0 = kbase + (size_t)l31 * NQKV + hi8;
  const bf16* kp1 = kp0 + (size_t)32 * NQKV;

  // ---- V staging indices ----
  int vs_d[2], vs_s[2];
#pragma unroll
  for (int u = 0; u < 2; ++u) {
    int idx = u * 256 + tid;
    vs_d[u] = (idx & 31) * 2;
    vs_s[u] = (idx >> 5) * 4;
  }

  uint32_t vreg[2][4];
  // prefetch V tile 0
#pragma unroll
  for (int u = 0; u < 2; ++u)
#pragma unroll
    for (int j = 0; j < 4; ++j)
      vreg[u][j] = *(const uint32_t*)(vbase + (size_t)(vs_s[u] + j) * NQKV + vs_d[u]);

  const f32x16 zero16 = {0.f,0.f,0.f,0.f,0.f,0.f,0.f,0.f,0.f,0.f,0.f,0.f,0.f,0.f,0.f,0.f};
  f32x16 oacc[2];
  oacc[0] = zero16; oacc[1] = zero16;
  float lsum = 0.f;
  const float c2 = 0.125f * 1.44269504088896341f;   // scale * log2(e)

  for (int kt = 0; kt < 32; ++kt) {
    const int buf = kt & 1;
    // ---- write staged V regs to LDS (swizzled transpose) ----
#pragma unroll
    for (int u = 0; u < 2; ++u) {
      int d0 = vs_d[u], s0 = vs_s[u];
      int sw = s0 ^ (d0 & 56);
      u16x4 lo, hi;
#pragma unroll
      for (int j = 0; j < 4; ++j) {
        lo[j] = (unsigned short)(vreg[u][j] & 0xffffu);
        hi[j] = (unsigned short)(vreg[u][j] >> 16);
      }
      *(u16x4*)&Vs[buf][(d0 + 0) * 64 + sw] = lo;
      *(u16x4*)&Vs[buf][(d0 + 1) * 64 + sw] = hi;
    }
    __syncthreads();

    // ---- prefetch next V tile (hidden behind compute) ----
    {
      int ktn = (kt + 1 < 32) ? kt + 1 : 31;
      const bf16* vb = vbase + (size_t)ktn * 64 * NQKV;
#pragma unroll
      for (int u = 0; u < 2; ++u)
#pragma unroll
        for (int j = 0; j < 4; ++j)
          vreg[u][j] = *(const uint32_t*)(vb + (size_t)(vs_s[u] + j) * NQKV + vs_d[u]);
    }

    // ---- S^T = K.Q^T : K frags direct from global (16B/lane contiguous) ----
    f32x16 sacc[2];
    {
      uint4 kfa[4], kfb[4];
#pragma unroll
      for (int c = 0; c < 4; ++c) kfa[c] = *(const uint4*)(kp0 + c * 16);
#pragma unroll
      for (int c = 0; c < 4; ++c) kfb[c] = *(const uint4*)(kp1 + c * 16);
      sacc[0] = zero16; sacc[1] = zero16;
#pragma unroll
      for (int c = 0; c < 4; ++c)
        sacc[0] = __builtin_amdgcn_mfma_f32_32x32x16_bf16(
            __builtin_bit_cast(bf16x8, kfa[c]), qf[c], sacc[0], 0, 0, 0);
#pragma unroll
      for (int c = 0; c < 4; ++c)
        sacc[1] = __builtin_amdgcn_mfma_f32_32x32x16_bf16(
            __builtin_bit_cast(bf16x8, kfb[c]), qf[c], sacc[1], 0, 0, 0);
    }
    kp0 += (size_t)64 * NQKV;
    kp1 += (size_t)64 * NQKV;

    // ---- p = 2^(s*c2 - 16); pack to dwords; psum ----
    uint32_t Q8[2][8];
    float psum = 0.f;
#pragma unroll
    for (int kk = 0; kk < 2; ++kk) {
#pragma unroll
      for (int i = 0; i < 8; ++i) {
        float p0 = __builtin_amdgcn_exp2f(sacc[kk][2 * i]     * c2 - 16.0f);
        float p1 = __builtin_amdgcn_exp2f(sacc[kk][2 * i + 1] * c2 - 16.0f);
        psum += p0 + p1;
        Q8[kk][i] = pkbf16(p0, p1);
      }
    }
    psum += __shfl_xor(psum, 32);
    lsum += psum;

    // ---- P C-layout -> B-frag via lane^32 exchange; O^T += Vt.P ----
#pragma unroll
    for (int m = 0; m < 4; ++m) {
      const int kk = m >> 1, bq = (m & 1) * 4;
      uint32_t s0 = e ? Q8[kk][bq]     : Q8[kk][bq + 2];
      uint32_t s1 = e ? Q8[kk][bq + 1] : Q8[kk][bq + 3];
      uint32_t r0 = __shfl_xor(s0, 32);
      uint32_t r1 = __shfl_xor(s1, 32);
      u32x4 pd;
      pd[0] = e ? r0 : Q8[kk][bq];
      pd[1] = e ? r1 : Q8[kk][bq + 1];
      pd[2] = e ? Q8[kk][bq + 2] : r0;
      pd[3] = e ? Q8[kk][bq + 3] : r1;
      bf16x8 pf = __builtin_bit_cast(bf16x8, pd);
#pragma unroll
      for (int dt = 0; dt < 2; ++dt) {
        int drow = dt * 32 + l31;
        int swv  = drow & 56;
        bf16x8 vf = *(const bf16x8*)&Vs[buf][drow * 64 + ((m * 16 + hi8) ^ swv)];
        oacc[dt] = __builtin_amdgcn_mfma_f32_32x32x16_bf16(vf, pf, oacc[dt], 0, 0, 0);
      }
    }
  }

  // ---- epilogue: O^T/lsum -> LDS (swizzled) -> coalesced 16B global stores ----
  __syncthreads();                       // all Vs reads done; safe to reuse as O-stage
  bf16* Os = (bf16*)Vs;                  // [128][64] bf16, col ^ ((row&7)*8)
  {
    float inv = 1.f / lsum;
    int ql = wq * 32 + l31;
    int swO = (ql & 7) * 8;
#pragma unroll
    for (int dt = 0; dt < 2; ++dt) {
#pragma unroll
      for (int g = 0; g < 4; ++g) {
        bf16x4 ov;
#pragma unroll
        for (int jj = 0; jj < 4; ++jj) ov[jj] = (bf16)(oacc[dt][g * 4 + jj] * inv);
        int d0 = dt * 32 + g * 8 + hi4;
        *(bf16x4*)&Os[ql * 64 + (d0 ^ swO)] = ov;
      }
    }
  }
  __syncthreads();
#pragma unroll
  for (int it = 0; it < 4; ++it) {
    int idx = it * 256 + tid;
    int row = idx >> 3, c8 = (idx & 7) * 8;
    bf16x8 t = *(const bf16x8*)&Os[row * 64 + (c8 ^ ((row & 7) * 8))];
    *(bf16x8*)&out[(rowb + q0 + row) * D_ + h * HD_ + c8] = t;
  }
}

extern "C" void kernel_launch(void* const* d_in, const int* in_sizes, int n_in,
                              void* d_out, int out_size, void* d_ws, size_t ws_size,
                              hipStream_t stream) {
  const float* x     = (const float*)d_in[0];
  const float* w_qkv = (const float*)d_in[1];
  const float* b_qkv = (const float*)d_in[2];
  const float* w_out = (const float*)d_in[3];
  const float* b_out = (const float*)d_in[4];
  float* out = (float*)d_out;

  char* ws = (char*)d_ws;
  bf16* xb    = (bf16*)(ws);                         // 16 MB
  bf16* wqkvT = (bf16*)(ws + (size_t)16777216);      //  6 MB
  bf16* woutT = (bf16*)(ws + (size_t)23068672);      //  2 MB
  bf16* qkvb  = (bf16*)(ws + (size_t)25165824);      // 48 MB
  bf16* attnb = (bf16*)(ws + (size_t)75497472);      // 16 MB

  cast_f32_bf16<<<(M_ * D_ / 4 + 255) / 256, 256, 0, stream>>>(x, xb, M_ * D_ / 4);
  transpose_cast<<<dim3(NQKV / 32, D_ / 32), dim3(32, 8), 0, stream>>>(w_qkv, wqkvT, D_, NQKV);
  transpose_cast<<<dim3(D_ / 32, D_ / 32), dim3(32, 8), 0, stream>>>(w_out, woutT, D_, D_);

  gemm_bt<true><<<dim3(NQKV / 128, M_ / 128), 256, 0, stream>>>(
      xb, wqkvT, b_qkv, (void*)qkvb, M_, NQKV, D_);

  flash_attn<<<B_ * H_ * (S_ / 128), 256, 0, stream>>>(qkvb, attnb);

  gemm_bt<false><<<dim3(D_ / 128, M_ / 128), 256, 0, stream>>>(
      attnb, woutT, b_out, (void*)out, M_, D_, D_);
}

// Round 5
// 347.763 us; speedup vs baseline: 1.0354x; 1.0354x over previous
//
#include <hip/hip_runtime.h>
#include <cstdint>
#include <cstddef>

// ---- problem constants ----
#define B_    4
#define S_    2048
#define D_    1024
#define H_    16
#define HD_   64
#define M_    8192      // B_*S_
#define NQKV  3072

typedef __bf16 bf16;
typedef __bf16 bf16x4 __attribute__((ext_vector_type(4)));
typedef __bf16 bf16x8 __attribute__((ext_vector_type(8)));
typedef float  f32x4  __attribute__((ext_vector_type(4)));
typedef float  f32x16 __attribute__((ext_vector_type(16)));
typedef unsigned short u16x4 __attribute__((ext_vector_type(4)));
typedef uint32_t u32x4 __attribute__((ext_vector_type(4)));

// async global->LDS, 16B per lane. LDS dest is wave-uniform base + lane*16.
__device__ __forceinline__ void gl2lds16(const void* g, void* l) {
  __builtin_amdgcn_global_load_lds(
      (__attribute__((address_space(1))) void*)(uintptr_t)g,
      (__attribute__((address_space(3))) void*)l, 16, 0, 0);
}

__device__ __forceinline__ uint32_t pkbf16(float a, float b) {
  union { bf16 h[2]; uint32_t u; } z;
  z.h[0] = (bf16)a; z.h[1] = (bf16)b;
  return z.u;
}

// ---- prep: fp32 -> bf16 cast (x) ----
__global__ __launch_bounds__(256) void cast_f32_bf16(const float* __restrict__ in,
                                                     bf16* __restrict__ out, int n4) {
  int i = blockIdx.x * 256 + threadIdx.x;
  if (i >= n4) return;
  float4 v = ((const float4*)in)[i];
  bf16x4 o;
  o[0] = (bf16)v.x; o[1] = (bf16)v.y; o[2] = (bf16)v.z; o[3] = (bf16)v.w;
  ((bf16x4*)out)[i] = o;
}

// ---- prep: transpose + cast: in [R,C] fp32 -> out [C,R] bf16 ----
__global__ __launch_bounds__(256) void transpose_cast(const float* __restrict__ in,
                                                      bf16* __restrict__ out, int R, int C) {
  __shared__ float tile[32][33];
  int bx = blockIdx.x * 32, by = blockIdx.y * 32;
  int tx = threadIdx.x, ty = threadIdx.y;
#pragma unroll
  for (int i = 0; i < 32; i += 8)
    tile[ty + i][tx] = in[(size_t)(by + ty + i) * C + bx + tx];
  __syncthreads();
#pragma unroll
  for (int i = 0; i < 32; i += 8)
    out[(size_t)(bx + ty + i) * R + by + tx] = (bf16)tile[tx][ty + i];
}

// ---- m97-style GEMM: C[M,N] = A[M,K] * Bt[N,K]^T + bias ----
template <bool OUT_BF16>
__global__ __launch_bounds__(256) void gemm_bt(const bf16* __restrict__ A,
                                               const bf16* __restrict__ Bt,
                                               const float* __restrict__ bias,
                                               void* __restrict__ Cptr,
                                               int M, int N, int K) {
  __shared__ __align__(16) bf16 As[128 * 64];
  __shared__ __align__(16) bf16 Bs[128 * 64];
  const int tid  = threadIdx.x;
  const int lane = tid & 63, w = tid >> 6;
  const int lo   = lane & 15, quad = lane >> 4;
  const int bm = blockIdx.y * 128, bn = blockIdx.x * 128;
  const int wm = (w >> 1) * 64,    wn = (w & 1) * 64;

  f32x4 acc[4][4];
  const f32x4 zero = {0.f, 0.f, 0.f, 0.f};
#pragma unroll
  for (int i = 0; i < 4; ++i)
#pragma unroll
    for (int j = 0; j < 4; ++j) acc[i][j] = zero;

  for (int k0 = 0; k0 < K; k0 += 64) {
#pragma unroll
    for (int c = 0; c < 4; ++c) {
      int seg = c * 4 + w;
      int idx = seg * 512 + lane * 8;
      int row = idx >> 6, col = idx & 63;
      gl2lds16(A  + (size_t)(bm + row) * K + k0 + col, As + seg * 512);
      gl2lds16(Bt + (size_t)(bn + row) * K + k0 + col, Bs + seg * 512);
    }
    __syncthreads();
#pragma unroll
    for (int ks = 0; ks < 2; ++ks) {
      bf16x8 av[4], bv[4];
#pragma unroll
      for (int i = 0; i < 4; ++i)
        av[i] = *(const bf16x8*)&As[(wm + i * 16 + lo) * 64 + ks * 32 + quad * 8];
#pragma unroll
      for (int j = 0; j < 4; ++j)
        bv[j] = *(const bf16x8*)&Bs[(wn + j * 16 + lo) * 64 + ks * 32 + quad * 8];
#pragma unroll
      for (int i = 0; i < 4; ++i)
#pragma unroll
        for (int j = 0; j < 4; ++j)
          acc[i][j] = __builtin_amdgcn_mfma_f32_16x16x32_bf16(av[i], bv[j], acc[i][j], 0, 0, 0);
    }
    __syncthreads();
  }
#pragma unroll
  for (int j = 0; j < 4; ++j) {
    int cg = bn + wn + j * 16 + lo;
    float bsv = bias[cg];
#pragma unroll
    for (int i = 0; i < 4; ++i) {
      int rg = bm + wm + i * 16 + quad * 4;
#pragma unroll
      for (int r = 0; r < 4; ++r) {
        float v = acc[i][j][r] + bsv;
        if (OUT_BF16) ((bf16*)Cptr)[(size_t)(rg + r) * N + cg] = (bf16)v;
        else          ((float*)Cptr)[(size_t)(rg + r) * N + cg] = v;
      }
    }
  }
}

#define VSTR 72   // Vt LDS row stride (elements): 144 B == 4 dwords mod 32 banks

// ---- flash attention v5 ----
// 128 q/block, 4 waves x 32 q, 32x32x16 MFMA. S^T = K.Q^T, O^T = Vt.P (q = C-col =
// lane&31 -> softmax in-lane). Fixed exponent offset (p = 2^(s*c2-16); exact pow2
// scaling cancels in O/lsum). K via double-buffered LDS, (s&7)*8 XOR swizzle
// (conflict-free writes AND b128 reads — R3-verified). V via double-buffered LDS
// transpose with PAD-72 row stride (free b128 reads: lane starts 4*l31 cover all 32
// banks; writes 2x-over-floor only). P C-layout -> B-frag via 2x shfl_xor(32).
// Epilogue: O -> LDS (swizzled, reuses Ks) -> coalesced 16B global stores.
__global__ __launch_bounds__(256, 4) void flash_attn(const bf16* __restrict__ qkv,
                                                     bf16* __restrict__ out) {
  __shared__ __align__(16) bf16 Ks[2][64 * 64];    // 16 KB; reused as O-stage
  __shared__ __align__(16) bf16 Vs[2][64 * VSTR];  // 18.4 KB, [d][s] pad-72

  const int tid  = threadIdx.x;
  const int lane = tid & 63, wq = tid >> 6;
  const int l31  = lane & 31;
  const int e    = lane >> 5;           // hi1
  const int hi8  = e * 8, hi4 = e * 4;

  const int bid = blockIdx.x;
  const int qb  = bid >> 6;             // 0..15
  const int bh  = bid & 63;
  const int h   = bh & 15;
  const int b   = bh >> 4;
  const int q0  = qb * 128;
  const size_t rowb = (size_t)b * S_;
  const bf16* qbase = qkv + rowb * NQKV + h * HD_;
  const bf16* kbase = qbase + D_;
  const bf16* vbase = qbase + 2 * D_;

  // ---- Q fragments straight from global (loop-invariant) ----
  bf16x8 qf[4];
  {
    const bf16* qrow = qbase + (size_t)(q0 + wq * 32 + l31) * NQKV;
#pragma unroll
    for (int c = 0; c < 4; ++c)
      qf[c] = *(const bf16x8*)(qrow + c * 16 + hi8);
  }

  // ---- staging index precompute ----
  int ks_s[2], ks_d[2];
#pragma unroll
  for (int c = 0; c < 2; ++c) {
    int idx = c * 256 + tid;
    ks_s[c] = idx >> 3;
    ks_d[c] = (idx & 7) * 8;
  }
  int vs_d[2], vs_s[2];
#pragma unroll
  for (int u = 0; u < 2; ++u) {
    int idx = u * 256 + tid;
    vs_d[u] = (idx & 31) * 2;
    vs_s[u] = (idx >> 5) * 4;
  }

  uint4 kreg[2];
  uint32_t vreg[2][4];

  // prefetch tile 0
#pragma unroll
  for (int c = 0; c < 2; ++c)
    kreg[c] = *(const uint4*)(kbase + (size_t)ks_s[c] * NQKV + ks_d[c]);
#pragma unroll
  for (int u = 0; u < 2; ++u)
#pragma unroll
    for (int j = 0; j < 4; ++j)
      vreg[u][j] = *(const uint32_t*)(vbase + (size_t)(vs_s[u] + j) * NQKV + vs_d[u]);

  const f32x16 zero16 = {0.f,0.f,0.f,0.f,0.f,0.f,0.f,0.f,0.f,0.f,0.f,0.f,0.f,0.f,0.f,0.f};
  f32x16 oacc[2];
  oacc[0] = zero16; oacc[1] = zero16;
  float lsum = 0.f;
  const float c2 = 0.125f * 1.44269504088896341f;   // scale * log2(e)

  for (int kt = 0; kt < 32; ++kt) {
    const int buf = kt & 1;
    // ---- write staged regs to LDS ----
#pragma unroll
    for (int c = 0; c < 2; ++c) {
      int s = ks_s[c], d0 = ks_d[c];
      *(uint4*)&Ks[buf][s * 64 + (d0 ^ ((s & 7) * 8))] = kreg[c];
    }
#pragma unroll
    for (int u = 0; u < 2; ++u) {
      int d0 = vs_d[u], s0 = vs_s[u];
      u16x4 lo, hi;
#pragma unroll
      for (int j = 0; j < 4; ++j) {
        lo[j] = (unsigned short)(vreg[u][j] & 0xffffu);
        hi[j] = (unsigned short)(vreg[u][j] >> 16);
      }
      *(u16x4*)&Vs[buf][(d0 + 0) * VSTR + s0] = lo;
      *(u16x4*)&Vs[buf][(d0 + 1) * VSTR + s0] = hi;
    }
    __syncthreads();

    // ---- prefetch next tile (hidden behind compute) ----
    {
      int ktn = (kt + 1 < 32) ? kt + 1 : 31;
      const bf16* kb = kbase + (size_t)ktn * 64 * NQKV;
      const bf16* vb = vbase + (size_t)ktn * 64 * NQKV;
#pragma unroll
      for (int c = 0; c < 2; ++c)
        kreg[c] = *(const uint4*)(kb + (size_t)ks_s[c] * NQKV + ks_d[c]);
#pragma unroll
      for (int u = 0; u < 2; ++u)
#pragma unroll
        for (int j = 0; j < 4; ++j)
          vreg[u][j] = *(const uint32_t*)(vb + (size_t)(vs_s[u] + j) * NQKV + vs_d[u]);
    }

    // ---- S^T = K.Q^T : 2 tiles [32k x 32q] ----
    f32x16 sacc[2];
#pragma unroll
    for (int kk = 0; kk < 2; ++kk) {
      sacc[kk] = zero16;
      int srow = kk * 32 + l31;
      int swz  = (srow & 7) * 8;
#pragma unroll
      for (int c = 0; c < 4; ++c) {
        bf16x8 kf = *(const bf16x8*)&Ks[buf][srow * 64 + ((c * 16 + hi8) ^ swz)];
        sacc[kk] = __builtin_amdgcn_mfma_f32_32x32x16_bf16(kf, qf[c], sacc[kk], 0, 0, 0);
      }
    }

    // ---- p = 2^(s*c2 - 16); pack to dwords; psum ----
    uint32_t Q8[2][8];
    float psum = 0.f;
#pragma unroll
    for (int kk = 0; kk < 2; ++kk) {
#pragma unroll
      for (int i = 0; i < 8; ++i) {
        float p0 = __builtin_amdgcn_exp2f(sacc[kk][2 * i]     * c2 - 16.0f);
        float p1 = __builtin_amdgcn_exp2f(sacc[kk][2 * i + 1] * c2 - 16.0f);
        psum += p0 + p1;
        Q8[kk][i] = pkbf16(p0, p1);
      }
    }
    psum += __shfl_xor(psum, 32);
    lsum += psum;

    // ---- P C-layout -> B-frag via lane^32 exchange; O^T += Vt.P ----
#pragma unroll
    for (int m = 0; m < 4; ++m) {
      const int kk = m >> 1, bq = (m & 1) * 4;
      uint32_t s0 = e ? Q8[kk][bq]     : Q8[kk][bq + 2];
      uint32_t s1 = e ? Q8[kk][bq + 1] : Q8[kk][bq + 3];
      uint32_t r0 = __shfl_xor(s0, 32);
      uint32_t r1 = __shfl_xor(s1, 32);
      u32x4 pd;
      pd[0] = e ? r0 : Q8[kk][bq];
      pd[1] = e ? r1 : Q8[kk][bq + 1];
      pd[2] = e ? Q8[kk][bq + 2] : r0;
      pd[3] = e ? Q8[kk][bq + 3] : r1;
      bf16x8 pf = __builtin_bit_cast(bf16x8, pd);
#pragma unroll
      for (int dt = 0; dt < 2; ++dt) {
        int drow = dt * 32 + l31;
        bf16x8 vf = *(const bf16x8*)&Vs[buf][drow * VSTR + m * 16 + hi8];
        oacc[dt] = __builtin_amdgcn_mfma_f32_32x32x16_bf16(vf, pf, oacc[dt], 0, 0, 0);
      }
    }
  }

  // ---- epilogue: O^T/lsum -> LDS (swizzled, reuse Ks) -> coalesced 16B stores ----
  __syncthreads();                       // all Ks/Vs reads done; safe to reuse
  bf16* Os = (bf16*)Ks;                  // [128][64] bf16, col ^ ((row&7)*8)
  {
    float inv = 1.f / lsum;
    int ql = wq * 32 + l31;
    int swO = (ql & 7) * 8;
#pragma unroll
    for (int dt = 0; dt < 2; ++dt) {
#pragma unroll
      for (int g = 0; g < 4; ++g) {
        bf16x4 ov;
#pragma unroll
        for (int jj = 0; jj < 4; ++jj) ov[jj] = (bf16)(oacc[dt][g * 4 + jj] * inv);
        int d0 = dt * 32 + g * 8 + hi4;
        *(bf16x4*)&Os[ql * 64 + (d0 ^ swO)] = ov;
      }
    }
  }
  __syncthreads();
#pragma unroll
  for (int it = 0; it < 4; ++it) {
    int idx = it * 256 + tid;
    int row = idx >> 3, c8 = (idx & 7) * 8;
    bf16x8 t = *(const bf16x8*)&Os[row * 64 + (c8 ^ ((row & 7) * 8))];
    *(bf16x8*)&out[(rowb + q0 + row) * D_ + h * HD_ + c8] = t;
  }
}

extern "C" void kernel_launch(void* const* d_in, const int* in_sizes, int n_in,
                              void* d_out, int out_size, void* d_ws, size_t ws_size,
                              hipStream_t stream) {
  const float* x     = (const float*)d_in[0];
  const float* w_qkv = (const float*)d_in[1];
  const float* b_qkv = (const float*)d_in[2];
  const float* w_out = (const float*)d_in[3];
  const float* b_out = (const float*)d_in[4];
  float* out = (float*)d_out;

  char* ws = (char*)d_ws;
  bf16* xb    = (bf16*)(ws);                         // 16 MB
  bf16* wqkvT = (bf16*)(ws + (size_t)16777216);      //  6 MB
  bf16* woutT = (bf16*)(ws + (size_t)23068672);      //  2 MB
  bf16* qkvb  = (bf16*)(ws + (size_t)25165824);      // 48 MB
  bf16* attnb = (bf16*)(ws + (size_t)75497472);      // 16 MB

  cast_f32_bf16<<<(M_ * D_ / 4 + 255) / 256, 256, 0, stream>>>(x, xb, M_ * D_ / 4);
  transpose_cast<<<dim3(NQKV / 32, D_ / 32), dim3(32, 8), 0, stream>>>(w_qkv, wqkvT, D_, NQKV);
  transpose_cast<<<dim3(D_ / 32, D_ / 32), dim3(32, 8), 0, stream>>>(w_out, woutT, D_, D_);

  gemm_bt<true><<<dim3(NQKV / 128, M_ / 128), 256, 0, stream>>>(
      xb, wqkvT, b_qkv, (void*)qkvb, M_, NQKV, D_);

  flash_attn<<<B_ * H_ * (S_ / 128), 256, 0, stream>>>(qkvb, attnb);

  gemm_bt<false><<<dim3(D_ / 128, M_ / 128), 256, 0, stream>>>(
      attnb, woutT, b_out, (void*)out, M_, D_, D_);
}

// Round 6
// 331.383 us; speedup vs baseline: 1.0866x; 1.0494x over previous
//
#include <hip/hip_runtime.h>
#include <cstdint>
#include <cstddef>

// ---- problem constants ----
#define B_    4
#define S_    2048
#define D_    1024
#define H_    16
#define HD_   64
#define M_    8192      // B_*S_
#define NQKV  3072

typedef __bf16 bf16;
typedef __bf16 bf16x4 __attribute__((ext_vector_type(4)));
typedef __bf16 bf16x8 __attribute__((ext_vector_type(8)));
typedef float  f32x4  __attribute__((ext_vector_type(4)));
typedef float  f32x16 __attribute__((ext_vector_type(16)));
typedef unsigned short u16x4 __attribute__((ext_vector_type(4)));
typedef uint32_t u32x4 __attribute__((ext_vector_type(4)));

// async global->LDS, 16B per lane. LDS dest is wave-uniform base + lane*16.
__device__ __forceinline__ void gl2lds16(const void* g, void* l) {
  __builtin_amdgcn_global_load_lds(
      (__attribute__((address_space(1))) void*)(uintptr_t)g,
      (__attribute__((address_space(3))) void*)l, 16, 0, 0);
}

__device__ __forceinline__ uint32_t pkbf16(float a, float b) {
  union { bf16 h[2]; uint32_t u; } z;
  z.h[0] = (bf16)a; z.h[1] = (bf16)b;
  return z.u;
}

// ---- prep: fp32 -> bf16 cast (x) ----
__global__ __launch_bounds__(256) void cast_f32_bf16(const float* __restrict__ in,
                                                     bf16* __restrict__ out, int n4) {
  int i = blockIdx.x * 256 + threadIdx.x;
  if (i >= n4) return;
  float4 v = ((const float4*)in)[i];
  bf16x4 o;
  o[0] = (bf16)v.x; o[1] = (bf16)v.y; o[2] = (bf16)v.z; o[3] = (bf16)v.w;
  ((bf16x4*)out)[i] = o;
}

// ---- prep: transpose + cast: in [R,C] fp32 -> out [C,R] bf16 ----
__global__ __launch_bounds__(256) void transpose_cast(const float* __restrict__ in,
                                                      bf16* __restrict__ out, int R, int C) {
  __shared__ float tile[32][33];
  int bx = blockIdx.x * 32, by = blockIdx.y * 32;
  int tx = threadIdx.x, ty = threadIdx.y;
#pragma unroll
  for (int i = 0; i < 32; i += 8)
    tile[ty + i][tx] = in[(size_t)(by + ty + i) * C + bx + tx];
  __syncthreads();
#pragma unroll
  for (int i = 0; i < 32; i += 8)
    out[(size_t)(bx + ty + i) * R + by + tx] = (bf16)tile[tx][ty + i];
}

// ---- m97-style GEMM: C[M,N] = A[M,K] * Bt[N,K]^T + bias ----
template <bool OUT_BF16>
__global__ __launch_bounds__(256) void gemm_bt(const bf16* __restrict__ A,
                                               const bf16* __restrict__ Bt,
                                               const float* __restrict__ bias,
                                               void* __restrict__ Cptr,
                                               int M, int N, int K) {
  __shared__ __align__(16) bf16 As[128 * 64];
  __shared__ __align__(16) bf16 Bs[128 * 64];
  const int tid  = threadIdx.x;
  const int lane = tid & 63, w = tid >> 6;
  const int lo   = lane & 15, quad = lane >> 4;
  const int bm = blockIdx.y * 128, bn = blockIdx.x * 128;
  const int wm = (w >> 1) * 64,    wn = (w & 1) * 64;

  f32x4 acc[4][4];
  const f32x4 zero = {0.f, 0.f, 0.f, 0.f};
#pragma unroll
  for (int i = 0; i < 4; ++i)
#pragma unroll
    for (int j = 0; j < 4; ++j) acc[i][j] = zero;

  for (int k0 = 0; k0 < K; k0 += 64) {
#pragma unroll
    for (int c = 0; c < 4; ++c) {
      int seg = c * 4 + w;
      int idx = seg * 512 + lane * 8;
      int row = idx >> 6, col = idx & 63;
      gl2lds16(A  + (size_t)(bm + row) * K + k0 + col, As + seg * 512);
      gl2lds16(Bt + (size_t)(bn + row) * K + k0 + col, Bs + seg * 512);
    }
    __syncthreads();
#pragma unroll
    for (int ks = 0; ks < 2; ++ks) {
      bf16x8 av[4], bv[4];
#pragma unroll
      for (int i = 0; i < 4; ++i)
        av[i] = *(const bf16x8*)&As[(wm + i * 16 + lo) * 64 + ks * 32 + quad * 8];
#pragma unroll
      for (int j = 0; j < 4; ++j)
        bv[j] = *(const bf16x8*)&Bs[(wn + j * 16 + lo) * 64 + ks * 32 + quad * 8];
#pragma unroll
      for (int i = 0; i < 4; ++i)
#pragma unroll
        for (int j = 0; j < 4; ++j)
          acc[i][j] = __builtin_amdgcn_mfma_f32_16x16x32_bf16(av[i], bv[j], acc[i][j], 0, 0, 0);
    }
    __syncthreads();
  }
#pragma unroll
  for (int j = 0; j < 4; ++j) {
    int cg = bn + wn + j * 16 + lo;
    float bsv = bias[cg];
#pragma unroll
    for (int i = 0; i < 4; ++i) {
      int rg = bm + wm + i * 16 + quad * 4;
#pragma unroll
      for (int r = 0; r < 4; ++r) {
        float v = acc[i][j][r] + bsv;
        if (OUT_BF16) ((bf16*)Cptr)[(size_t)(rg + r) * N + cg] = (bf16)v;
        else          ((float*)Cptr)[(size_t)(rg + r) * N + cg] = v;
      }
    }
  }
}

#define PSTR 72   // padded LDS row stride (elements): 144 B == 4 dwords mod 32 banks

// ---- flash attention v6 ----
// 128 q/block, 4 waves x 32 q, 32x32x16 MFMA. S^T = K.Q^T, O^T = Vt.P (q = C-col =
// lane&31 -> softmax in-lane). Fixed exponent offset (p = 2^(s*c2-16); exact pow2
// scaling cancels in O/lsum). K and Vt both in double-buffered pad-72 LDS
// (bank-floor writes AND b128 reads, no XOR VALU). P C-layout -> B-frag via
// 2x shfl_xor(32) per MFMA; softmax split per 32k-half to halve Q8 liveness and
// overlap exp2 with the other half's S-MFMAs. psum shfl hoisted out of the k-loop
// (sum of shfls == shfl of sum). launch_bounds (256,3): 170-reg budget, no spills
// (measured: (256,4) spilled -> 205 MB scratch writes; occupancy was 3 blocks anyway).
// Epilogue: O -> LDS (pad-72, reuses Ks) -> coalesced 16B global stores.
__global__ __launch_bounds__(256, 3) void flash_attn(const bf16* __restrict__ qkv,
                                                     bf16* __restrict__ out) {
  __shared__ __align__(16) bf16 Ks[2][64 * PSTR];  // 18.4 KB; reused as O-stage
  __shared__ __align__(16) bf16 Vs[2][64 * PSTR];  // 18.4 KB, [d][s]

  const int tid  = threadIdx.x;
  const int lane = tid & 63, wq = tid >> 6;
  const int l31  = lane & 31;
  const int e    = lane >> 5;           // hi1
  const int hi8  = e * 8, hi4 = e * 4;

  const int bid = blockIdx.x;
  const int qb  = bid >> 6;             // 0..15
  const int bh  = bid & 63;
  const int h   = bh & 15;
  const int b   = bh >> 4;
  const int q0  = qb * 128;
  const size_t rowb = (size_t)b * S_;
  const bf16* qbase = qkv + rowb * NQKV + h * HD_;
  const bf16* kbase = qbase + D_;
  const bf16* vbase = qbase + 2 * D_;

  // ---- Q fragments straight from global (loop-invariant) ----
  bf16x8 qf[4];
  {
    const bf16* qrow = qbase + (size_t)(q0 + wq * 32 + l31) * NQKV;
#pragma unroll
    for (int c = 0; c < 4; ++c)
      qf[c] = *(const bf16x8*)(qrow + c * 16 + hi8);
  }

  // ---- staging index precompute ----
  int ks_s[2], ks_d[2];
#pragma unroll
  for (int c = 0; c < 2; ++c) {
    int idx = c * 256 + tid;
    ks_s[c] = idx >> 3;
    ks_d[c] = (idx & 7) * 8;
  }
  int vs_d[2], vs_s[2];
#pragma unroll
  for (int u = 0; u < 2; ++u) {
    int idx = u * 256 + tid;
    vs_d[u] = (idx & 31) * 2;
    vs_s[u] = (idx >> 5) * 4;
  }

  uint4 kreg[2];
  uint32_t vreg[2][4];

  // prefetch tile 0
#pragma unroll
  for (int c = 0; c < 2; ++c)
    kreg[c] = *(const uint4*)(kbase + (size_t)ks_s[c] * NQKV + ks_d[c]);
#pragma unroll
  for (int u = 0; u < 2; ++u)
#pragma unroll
    for (int j = 0; j < 4; ++j)
      vreg[u][j] = *(const uint32_t*)(vbase + (size_t)(vs_s[u] + j) * NQKV + vs_d[u]);

  const f32x16 zero16 = {0.f,0.f,0.f,0.f,0.f,0.f,0.f,0.f,0.f,0.f,0.f,0.f,0.f,0.f,0.f,0.f};
  f32x16 oacc[2];
  oacc[0] = zero16; oacc[1] = zero16;
  float lsum = 0.f;                     // per-lane partial; cross-half shfl at epilogue
  const float c2 = 0.125f * 1.44269504088896341f;   // scale * log2(e)

  for (int kt = 0; kt < 32; ++kt) {
    const int buf = kt & 1;
    // ---- write staged regs to LDS (pad-72) ----
#pragma unroll
    for (int c = 0; c < 2; ++c)
      *(uint4*)&Ks[buf][ks_s[c] * PSTR + ks_d[c]] = kreg[c];
#pragma unroll
    for (int u = 0; u < 2; ++u) {
      int d0 = vs_d[u], s0 = vs_s[u];
      u16x4 lo, hi;
#pragma unroll
      for (int j = 0; j < 4; ++j) {
        lo[j] = (unsigned short)(vreg[u][j] & 0xffffu);
        hi[j] = (unsigned short)(vreg[u][j] >> 16);
      }
      *(u16x4*)&Vs[buf][(d0 + 0) * PSTR + s0] = lo;
      *(u16x4*)&Vs[buf][(d0 + 1) * PSTR + s0] = hi;
    }
    __syncthreads();

    // ---- prefetch next tile (hidden behind compute) ----
    {
      int ktn = (kt + 1 < 32) ? kt + 1 : 31;
      const bf16* kb = kbase + (size_t)ktn * 64 * NQKV;
      const bf16* vb = vbase + (size_t)ktn * 64 * NQKV;
#pragma unroll
      for (int c = 0; c < 2; ++c)
        kreg[c] = *(const uint4*)(kb + (size_t)ks_s[c] * NQKV + ks_d[c]);
#pragma unroll
      for (int u = 0; u < 2; ++u)
#pragma unroll
        for (int j = 0; j < 4; ++j)
          vreg[u][j] = *(const uint32_t*)(vb + (size_t)(vs_s[u] + j) * NQKV + vs_d[u]);
    }

    // ---- S^T = K.Q^T : 2 independent chains [32k x 32q] ----
    f32x16 sacc[2];
#pragma unroll
    for (int kk = 0; kk < 2; ++kk) {
      sacc[kk] = zero16;
      int srow = kk * 32 + l31;
#pragma unroll
      for (int c = 0; c < 4; ++c) {
        bf16x8 kf = *(const bf16x8*)&Ks[buf][srow * PSTR + c * 16 + hi8];
        sacc[kk] = __builtin_amdgcn_mfma_f32_32x32x16_bf16(kf, qf[c], sacc[kk], 0, 0, 0);
      }
    }

    // ---- per 32k-half: exp2 -> pack -> relayout -> O-MFMAs ----
#pragma unroll
    for (int kk = 0; kk < 2; ++kk) {
      uint32_t Q8[8];
      float ps = 0.f;
#pragma unroll
      for (int i = 0; i < 8; ++i) {
        float p0 = __builtin_amdgcn_exp2f(sacc[kk][2 * i]     * c2 - 16.0f);
        float p1 = __builtin_amdgcn_exp2f(sacc[kk][2 * i + 1] * c2 - 16.0f);
        ps += p0 + p1;
        Q8[i] = pkbf16(p0, p1);
      }
      lsum += ps;
#pragma unroll
      for (int mh = 0; mh < 2; ++mh) {
        const int m = kk * 2 + mh, bq = mh * 4;
        uint32_t s0 = e ? Q8[bq]     : Q8[bq + 2];
        uint32_t s1 = e ? Q8[bq + 1] : Q8[bq + 3];
        uint32_t r0 = __shfl_xor(s0, 32);
        uint32_t r1 = __shfl_xor(s1, 32);
        u32x4 pd;
        pd[0] = e ? r0 : Q8[bq];
        pd[1] = e ? r1 : Q8[bq + 1];
        pd[2] = e ? Q8[bq + 2] : r0;
        pd[3] = e ? Q8[bq + 3] : r1;
        bf16x8 pf = __builtin_bit_cast(bf16x8, pd);
#pragma unroll
        for (int dt = 0; dt < 2; ++dt) {
          int drow = dt * 32 + l31;
          bf16x8 vf = *(const bf16x8*)&Vs[buf][drow * PSTR + m * 16 + hi8];
          oacc[dt] = __builtin_amdgcn_mfma_f32_32x32x16_bf16(vf, pf, oacc[dt], 0, 0, 0);
        }
      }
    }
  }

  lsum += __shfl_xor(lsum, 32);

  // ---- epilogue: O^T/lsum -> LDS (pad-72, reuse Ks) -> coalesced 16B stores ----
  __syncthreads();                       // all Ks/Vs reads done; safe to reuse
  bf16* Os = (bf16*)Ks;                  // [128][PSTR] bf16 (128*72 = 9216 = 2*64*72)
  {
    float inv = 1.f / lsum;
    int ql = wq * 32 + l31;
#pragma unroll
    for (int dt = 0; dt < 2; ++dt) {
#pragma unroll
      for (int g = 0; g < 4; ++g) {
        bf16x4 ov;
#pragma unroll
        for (int jj = 0; jj < 4; ++jj) ov[jj] = (bf16)(oacc[dt][g * 4 + jj] * inv);
        *(bf16x4*)&Os[ql * PSTR + dt * 32 + g * 8 + hi4] = ov;
      }
    }
  }
  __syncthreads();
#pragma unroll
  for (int it = 0; it < 4; ++it) {
    int idx = it * 256 + tid;
    int row = idx >> 3, c8 = (idx & 7) * 8;
    bf16x8 t = *(const bf16x8*)&Os[row * PSTR + c8];
    *(bf16x8*)&out[(rowb + q0 + row) * D_ + h * HD_ + c8] = t;
  }
}

extern "C" void kernel_launch(void* const* d_in, const int* in_sizes, int n_in,
                              void* d_out, int out_size, void* d_ws, size_t ws_size,
                              hipStream_t stream) {
  const float* x     = (const float*)d_in[0];
  const float* w_qkv = (const float*)d_in[1];
  const float* b_qkv = (const float*)d_in[2];
  const float* w_out = (const float*)d_in[3];
  const float* b_out = (const float*)d_in[4];
  float* out = (float*)d_out;

  char* ws = (char*)d_ws;
  bf16* xb    = (bf16*)(ws);                         // 16 MB
  bf16* wqkvT = (bf16*)(ws + (size_t)16777216);      //  6 MB
  bf16* woutT = (bf16*)(ws + (size_t)23068672);      //  2 MB
  bf16* qkvb  = (bf16*)(ws + (size_t)25165824);      // 48 MB
  bf16* attnb = (bf16*)(ws + (size_t)75497472);      // 16 MB

  cast_f32_bf16<<<(M_ * D_ / 4 + 255) / 256, 256, 0, stream>>>(x, xb, M_ * D_ / 4);
  transpose_cast<<<dim3(NQKV / 32, D_ / 32), dim3(32, 8), 0, stream>>>(w_qkv, wqkvT, D_, NQKV);
  transpose_cast<<<dim3(D_ / 32, D_ / 32), dim3(32, 8), 0, stream>>>(w_out, woutT, D_, D_);

  gemm_bt<true><<<dim3(NQKV / 128, M_ / 128), 256, 0, stream>>>(
      xb, wqkvT, b_qkv, (void*)qkvb, M_, NQKV, D_);

  flash_attn<<<B_ * H_ * (S_ / 128), 256, 0, stream>>>(qkvb, attnb);

  gemm_bt<false><<<dim3(D_ / 128, M_ / 128), 256, 0, stream>>>(
      attnb, woutT, b_out, (void*)out, M_, D_, D_);
}

// Round 7
// 306.332 us; speedup vs baseline: 1.1754x; 1.0818x over previous
//
#include <hip/hip_runtime.h>
#include <cstdint>
#include <cstddef>

// ---- problem constants ----
#define B_    4
#define S_    2048
#define D_    1024
#define H_    16
#define HD_   64
#define M_    8192      // B_*S_
#define NQKV  3072

typedef __bf16 bf16;
typedef __bf16 bf16x4 __attribute__((ext_vector_type(4)));
typedef __bf16 bf16x8 __attribute__((ext_vector_type(8)));
typedef float  f32x4  __attribute__((ext_vector_type(4)));
typedef float  f32x16 __attribute__((ext_vector_type(16)));
typedef unsigned short u16x4 __attribute__((ext_vector_type(4)));
typedef uint32_t u32x4 __attribute__((ext_vector_type(4)));

// async global->LDS, 16B per lane. LDS dest is wave-uniform base + lane*16.
__device__ __forceinline__ void gl2lds16(const void* g, void* l) {
  __builtin_amdgcn_global_load_lds(
      (__attribute__((address_space(1))) void*)(uintptr_t)g,
      (__attribute__((address_space(3))) void*)l, 16, 0, 0);
}

__device__ __forceinline__ uint32_t pkbf16(float a, float b) {
  union { bf16 h[2]; uint32_t u; } z;
  z.h[0] = (bf16)a; z.h[1] = (bf16)b;
  return z.u;
}

// ---- prep: fp32 -> bf16 cast (x) ----
__global__ __launch_bounds__(256) void cast_f32_bf16(const float* __restrict__ in,
                                                     bf16* __restrict__ out, int n4) {
  int i = blockIdx.x * 256 + threadIdx.x;
  if (i >= n4) return;
  float4 v = ((const float4*)in)[i];
  bf16x4 o;
  o[0] = (bf16)v.x; o[1] = (bf16)v.y; o[2] = (bf16)v.z; o[3] = (bf16)v.w;
  ((bf16x4*)out)[i] = o;
}

// ---- prep: transpose + cast: in [R,C] fp32 -> out [C,R] bf16 ----
__global__ __launch_bounds__(256) void transpose_cast(const float* __restrict__ in,
                                                      bf16* __restrict__ out, int R, int C) {
  __shared__ float tile[32][33];
  int bx = blockIdx.x * 32, by = blockIdx.y * 32;
  int tx = threadIdx.x, ty = threadIdx.y;
#pragma unroll
  for (int i = 0; i < 32; i += 8)
    tile[ty + i][tx] = in[(size_t)(by + ty + i) * C + bx + tx];
  __syncthreads();
#pragma unroll
  for (int i = 0; i < 32; i += 8)
    out[(size_t)(bx + ty + i) * R + by + tx] = (bf16)tile[tx][ty + i];
}

// ---- m97-style GEMM with XCD super-tiling: C[M,N] = A[M,K]*Bt[N,K]^T + bias ----
// 1D grid of (M/128)*(N/128) blocks; bid&7 = XCD -> m-band of 8 tiles (A-band 2 MB,
// per-XCD-L2-resident); within band: mi-inner (8 adjacent blocks share each B-tile),
// n-outer. Requires M/128 == 64.
template <bool OUT_BF16>
__global__ __launch_bounds__(256) void gemm_bt(const bf16* __restrict__ A,
                                               const bf16* __restrict__ Bt,
                                               const float* __restrict__ bias,
                                               void* __restrict__ Cptr,
                                               int M, int N, int K) {
  __shared__ __align__(16) bf16 As[128 * 64];
  __shared__ __align__(16) bf16 Bs[128 * 64];
  const int tid  = threadIdx.x;
  const int lane = tid & 63, w = tid >> 6;
  const int lo   = lane & 15, quad = lane >> 4;
  const int xcd = blockIdx.x & 7, g = blockIdx.x >> 3;
  const int mi  = g & 7,          n = g >> 3;
  const int bm  = (xcd * 8 + mi) * 128, bn = n * 128;
  const int wm = (w >> 1) * 64,    wn = (w & 1) * 64;

  f32x4 acc[4][4];
  const f32x4 zero = {0.f, 0.f, 0.f, 0.f};
#pragma unroll
  for (int i = 0; i < 4; ++i)
#pragma unroll
    for (int j = 0; j < 4; ++j) acc[i][j] = zero;

  for (int k0 = 0; k0 < K; k0 += 64) {
#pragma unroll
    for (int c = 0; c < 4; ++c) {
      int seg = c * 4 + w;
      int idx = seg * 512 + lane * 8;
      int row = idx >> 6, col = idx & 63;
      gl2lds16(A  + (size_t)(bm + row) * K + k0 + col, As + seg * 512);
      gl2lds16(Bt + (size_t)(bn + row) * K + k0 + col, Bs + seg * 512);
    }
    __syncthreads();
#pragma unroll
    for (int ks = 0; ks < 2; ++ks) {
      bf16x8 av[4], bv[4];
#pragma unroll
      for (int i = 0; i < 4; ++i)
        av[i] = *(const bf16x8*)&As[(wm + i * 16 + lo) * 64 + ks * 32 + quad * 8];
#pragma unroll
      for (int j = 0; j < 4; ++j)
        bv[j] = *(const bf16x8*)&Bs[(wn + j * 16 + lo) * 64 + ks * 32 + quad * 8];
#pragma unroll
      for (int i = 0; i < 4; ++i)
#pragma unroll
        for (int j = 0; j < 4; ++j)
          acc[i][j] = __builtin_amdgcn_mfma_f32_16x16x32_bf16(av[i], bv[j], acc[i][j], 0, 0, 0);
    }
    __syncthreads();
  }
#pragma unroll
  for (int j = 0; j < 4; ++j) {
    int cg = bn + wn + j * 16 + lo;
    float bsv = bias[cg];
#pragma unroll
    for (int i = 0; i < 4; ++i) {
      int rg = bm + wm + i * 16 + quad * 4;
#pragma unroll
      for (int r = 0; r < 4; ++r) {
        float v = acc[i][j][r] + bsv;
        if (OUT_BF16) ((bf16*)Cptr)[(size_t)(rg + r) * N + cg] = (bf16)v;
        else          ((float*)Cptr)[(size_t)(rg + r) * N + cg] = v;
      }
    }
  }
}

#define PSTR 72   // padded V LDS row stride (elements)

// ---- flash attention v7 ----
// 128 q/block, 4 waves x 32 q, 32x32x16 MFMA. S^T = K.Q^T, O^T = Vt.P (q = C-col =
// lane&31 -> softmax in-lane). Fixed exponent offset (p = 2^(s*c2-16); exact pow2
// scaling cancels in O/lsum). K staged via global_load_lds DMA one tile AHEAD with a
// 16B-chunk XOR permutation (lane ci loads global chunk (s=ci>>3, x=(ci&7)^(s&7)) ->
// LDS phys layout s*64 + (d8 ^ (s&7)*8); b128 frag reads at bank floor). V via
// register transpose into pad-72 LDS. P C-layout -> B-frag via 2x shfl_xor(32).
// launch_bounds (256,4): arch VGPR ~60 + 64 acc fits 128 (spill tripwire: WRITE_SIZE).
// Epilogue: O -> LDS (reuses Vs) -> coalesced 16B global stores.
__global__ __launch_bounds__(256, 4) void flash_attn(const bf16* __restrict__ qkv,
                                                     bf16* __restrict__ out) {
  __shared__ __align__(16) bf16 Ks[2][64 * 64];    // 16 KB, chunk-swizzled rows
  __shared__ __align__(16) bf16 Vs[2][64 * PSTR];  // 18 KB, [d][s]; reused as O-stage

  const int tid  = threadIdx.x;
  const int lane = tid & 63, wq = tid >> 6;
  const int l31  = lane & 31;
  const int e    = lane >> 5;           // hi1
  const int hi8  = e * 8, hi4 = e * 4;

  const int bid = blockIdx.x;
  const int qb  = bid >> 6;             // 0..15
  const int bh  = bid & 63;
  const int h   = bh & 15;
  const int b   = bh >> 4;
  const int q0  = qb * 128;
  const size_t rowb = (size_t)b * S_;
  const bf16* qbase = qkv + rowb * NQKV + h * HD_;
  const bf16* kbase = qbase + D_;
  const bf16* vbase = qbase + 2 * D_;

  // ---- Q fragments straight from global (loop-invariant) ----
  bf16x8 qf[4];
  {
    const bf16* qrow = qbase + (size_t)(q0 + wq * 32 + l31) * NQKV;
#pragma unroll
    for (int c = 0; c < 4; ++c)
      qf[c] = *(const bf16x8*)(qrow + c * 16 + hi8);
  }

  // ---- K DMA indices: chunk ci = it*256+tid -> global (s, x), LDS = contiguous ----
  int kq_off[2];        // global element offset for this lane's chunk, per it
#pragma unroll
  for (int it = 0; it < 2; ++it) {
    int ci = it * 256 + tid;
    int s  = ci >> 3;
    int x  = (ci & 7) ^ (s & 7);
    kq_off[it] = s * NQKV + x * 8;
  }
  // ---- V staging indices ----
  int vs_d[2], vs_s[2];
#pragma unroll
  for (int u = 0; u < 2; ++u) {
    int idx = u * 256 + tid;
    vs_d[u] = (idx & 31) * 2;
    vs_s[u] = (idx >> 5) * 4;
  }

  uint32_t vreg[2][4];

  // ---- prologue: DMA K tile 0 into buf0; prefetch V tile 0 regs ----
#pragma unroll
  for (int it = 0; it < 2; ++it)
    gl2lds16(kbase + kq_off[it], &Ks[0][(it * 256 + wq * 64) * 8]);
#pragma unroll
  for (int u = 0; u < 2; ++u)
#pragma unroll
    for (int j = 0; j < 4; ++j)
      vreg[u][j] = *(const uint32_t*)(vbase + (size_t)(vs_s[u] + j) * NQKV + vs_d[u]);

  const f32x16 zero16 = {0.f,0.f,0.f,0.f,0.f,0.f,0.f,0.f,0.f,0.f,0.f,0.f,0.f,0.f,0.f,0.f};
  f32x16 oacc[2];
  oacc[0] = zero16; oacc[1] = zero16;
  float lsum = 0.f;                     // per-lane partial; cross-half shfl at epilogue
  const float c2 = 0.125f * 1.44269504088896341f;   // scale * log2(e)

  for (int kt = 0; kt < 32; ++kt) {
    const int buf = kt & 1;
    // ---- write staged V regs to LDS (pad-72 transpose) ----
#pragma unroll
    for (int u = 0; u < 2; ++u) {
      int d0 = vs_d[u], s0 = vs_s[u];
      u16x4 lo, hi;
#pragma unroll
      for (int j = 0; j < 4; ++j) {
        lo[j] = (unsigned short)(vreg[u][j] & 0xffffu);
        hi[j] = (unsigned short)(vreg[u][j] >> 16);
      }
      *(u16x4*)&Vs[buf][(d0 + 0) * PSTR + s0] = lo;
      *(u16x4*)&Vs[buf][(d0 + 1) * PSTR + s0] = hi;
    }
    __syncthreads();

    // ---- async K DMA for NEXT tile into buf^1 (drained by next barrier) ----
    {
      int ktn = (kt + 1 < 32) ? kt + 1 : 31;
      const bf16* kb = kbase + (size_t)ktn * 64 * NQKV;
#pragma unroll
      for (int it = 0; it < 2; ++it)
        gl2lds16(kb + kq_off[it], &Ks[buf ^ 1][(it * 256 + wq * 64) * 8]);
    }
    // ---- V register prefetch for next tile ----
    {
      int ktn = (kt + 1 < 32) ? kt + 1 : 31;
      const bf16* vb = vbase + (size_t)ktn * 64 * NQKV;
#pragma unroll
      for (int u = 0; u < 2; ++u)
#pragma unroll
        for (int j = 0; j < 4; ++j)
          vreg[u][j] = *(const uint32_t*)(vb + (size_t)(vs_s[u] + j) * NQKV + vs_d[u]);
    }

    // ---- S^T = K.Q^T : 2 independent chains [32k x 32q], XOR-swizzled reads ----
    f32x16 sacc[2];
#pragma unroll
    for (int kk = 0; kk < 2; ++kk) {
      sacc[kk] = zero16;
      int srow = kk * 32 + l31;
      int swz  = (srow & 7) * 8;
#pragma unroll
      for (int c = 0; c < 4; ++c) {
        bf16x8 kf = *(const bf16x8*)&Ks[buf][srow * 64 + ((c * 16 + hi8) ^ swz)];
        sacc[kk] = __builtin_amdgcn_mfma_f32_32x32x16_bf16(kf, qf[c], sacc[kk], 0, 0, 0);
      }
    }

    // ---- per 32k-half: exp2 -> pack -> relayout -> O-MFMAs ----
#pragma unroll
    for (int kk = 0; kk < 2; ++kk) {
      uint32_t Q8[8];
      float ps = 0.f;
#pragma unroll
      for (int i = 0; i < 8; ++i) {
        float p0 = __builtin_amdgcn_exp2f(sacc[kk][2 * i]     * c2 - 16.0f);
        float p1 = __builtin_amdgcn_exp2f(sacc[kk][2 * i + 1] * c2 - 16.0f);
        ps += p0 + p1;
        Q8[i] = pkbf16(p0, p1);
      }
      lsum += ps;
#pragma unroll
      for (int mh = 0; mh < 2; ++mh) {
        const int m = kk * 2 + mh, bq = mh * 4;
        uint32_t s0 = e ? Q8[bq]     : Q8[bq + 2];
        uint32_t s1 = e ? Q8[bq + 1] : Q8[bq + 3];
        uint32_t r0 = __shfl_xor(s0, 32);
        uint32_t r1 = __shfl_xor(s1, 32);
        u32x4 pd;
        pd[0] = e ? r0 : Q8[bq];
        pd[1] = e ? r1 : Q8[bq + 1];
        pd[2] = e ? Q8[bq + 2] : r0;
        pd[3] = e ? Q8[bq + 3] : r1;
        bf16x8 pf = __builtin_bit_cast(bf16x8, pd);
#pragma unroll
        for (int dt = 0; dt < 2; ++dt) {
          int drow = dt * 32 + l31;
          bf16x8 vf = *(const bf16x8*)&Vs[buf][drow * PSTR + m * 16 + hi8];
          oacc[dt] = __builtin_amdgcn_mfma_f32_32x32x16_bf16(vf, pf, oacc[dt], 0, 0, 0);
        }
      }
    }
  }

  lsum += __shfl_xor(lsum, 32);

  // ---- epilogue: O^T/lsum -> LDS (pad-72, reuse Vs) -> coalesced 16B stores ----
  __syncthreads();                       // all Ks/Vs reads done; safe to reuse
  bf16* Os = (bf16*)Vs;                  // [128][PSTR] bf16 (128*72 == 2*64*72)
  {
    float inv = 1.f / lsum;
    int ql = wq * 32 + l31;
#pragma unroll
    for (int dt = 0; dt < 2; ++dt) {
#pragma unroll
      for (int g = 0; g < 4; ++g) {
        bf16x4 ov;
#pragma unroll
        for (int jj = 0; jj < 4; ++jj) ov[jj] = (bf16)(oacc[dt][g * 4 + jj] * inv);
        *(bf16x4*)&Os[ql * PSTR + dt * 32 + g * 8 + hi4] = ov;
      }
    }
  }
  __syncthreads();
#pragma unroll
  for (int it = 0; it < 4; ++it) {
    int idx = it * 256 + tid;
    int row = idx >> 3, c8 = (idx & 7) * 8;
    bf16x8 t = *(const bf16x8*)&Os[row * PSTR + c8];
    *(bf16x8*)&out[(rowb + q0 + row) * D_ + h * HD_ + c8] = t;
  }
}

extern "C" void kernel_launch(void* const* d_in, const int* in_sizes, int n_in,
                              void* d_out, int out_size, void* d_ws, size_t ws_size,
                              hipStream_t stream) {
  const float* x     = (const float*)d_in[0];
  const float* w_qkv = (const float*)d_in[1];
  const float* b_qkv = (const float*)d_in[2];
  const float* w_out = (const float*)d_in[3];
  const float* b_out = (const float*)d_in[4];
  float* out = (float*)d_out;

  char* ws = (char*)d_ws;
  bf16* xb    = (bf16*)(ws);                         // 16 MB
  bf16* wqkvT = (bf16*)(ws + (size_t)16777216);      //  6 MB
  bf16* woutT = (bf16*)(ws + (size_t)23068672);      //  2 MB
  bf16* qkvb  = (bf16*)(ws + (size_t)25165824);      // 48 MB
  bf16* attnb = (bf16*)(ws + (size_t)75497472);      // 16 MB

  cast_f32_bf16<<<(M_ * D_ / 4 + 255) / 256, 256, 0, stream>>>(x, xb, M_ * D_ / 4);
  transpose_cast<<<dim3(NQKV / 32, D_ / 32), dim3(32, 8), 0, stream>>>(w_qkv, wqkvT, D_, NQKV);
  transpose_cast<<<dim3(D_ / 32, D_ / 32), dim3(32, 8), 0, stream>>>(w_out, woutT, D_, D_);

  gemm_bt<true><<<(M_ / 128) * (NQKV / 128), 256, 0, stream>>>(
      xb, wqkvT, b_qkv, (void*)qkvb, M_, NQKV, D_);

  flash_attn<<<B_ * H_ * (S_ / 128), 256, 0, stream>>>(qkvb, attnb);

  gemm_bt<false><<<(M_ / 128) * (D_ / 128), 256, 0, stream>>>(
      attnb, woutT, b_out, (void*)out, M_, D_, D_);
}

// Round 8
// 303.316 us; speedup vs baseline: 1.1871x; 1.0099x over previous
//
#include <hip/hip_runtime.h>
#include <cstdint>
#include <cstddef>

// ---- problem constants ----
#define B_    4
#define S_    2048
#define D_    1024
#define H_    16
#define HD_   64
#define M_    8192      // B_*S_
#define NQKV  3072

typedef __bf16 bf16;
typedef __bf16 bf16x4 __attribute__((ext_vector_type(4)));
typedef __bf16 bf16x8 __attribute__((ext_vector_type(8)));
typedef float  f32x4  __attribute__((ext_vector_type(4)));
typedef float  f32x16 __attribute__((ext_vector_type(16)));
typedef unsigned short u16x4 __attribute__((ext_vector_type(4)));
typedef uint32_t u32x4 __attribute__((ext_vector_type(4)));

// async global->LDS, 16B per lane. LDS dest is wave-uniform base + lane*16.
__device__ __forceinline__ void gl2lds16(const void* g, void* l) {
  __builtin_amdgcn_global_load_lds(
      (__attribute__((address_space(1))) void*)(uintptr_t)g,
      (__attribute__((address_space(3))) void*)l, 16, 0, 0);
}

__device__ __forceinline__ uint32_t pkbf16(float a, float b) {
  union { bf16 h[2]; uint32_t u; } z;
  z.h[0] = (bf16)a; z.h[1] = (bf16)b;
  return z.u;
}

// ---- prep: fp32 -> bf16 cast (x) ----
__global__ __launch_bounds__(256) void cast_f32_bf16(const float* __restrict__ in,
                                                     bf16* __restrict__ out, int n4) {
  int i = blockIdx.x * 256 + threadIdx.x;
  if (i >= n4) return;
  float4 v = ((const float4*)in)[i];
  bf16x4 o;
  o[0] = (bf16)v.x; o[1] = (bf16)v.y; o[2] = (bf16)v.z; o[3] = (bf16)v.w;
  ((bf16x4*)out)[i] = o;
}

// ---- prep: transpose + cast: in [R,C] fp32 -> out [C,R] bf16 ----
__global__ __launch_bounds__(256) void transpose_cast(const float* __restrict__ in,
                                                      bf16* __restrict__ out, int R, int C) {
  __shared__ float tile[32][33];
  int bx = blockIdx.x * 32, by = blockIdx.y * 32;
  int tx = threadIdx.x, ty = threadIdx.y;
#pragma unroll
  for (int i = 0; i < 32; i += 8)
    tile[ty + i][tx] = in[(size_t)(by + ty + i) * C + bx + tx];
  __syncthreads();
#pragma unroll
  for (int i = 0; i < 32; i += 8)
    out[(size_t)(bx + ty + i) * R + by + tx] = (bf16)tile[tx][ty + i];
}

// ---- 128x128 GEMM w/ XCD super-tiling: C[M,N] = A[M,K]*Bt[N,K]^T + bias ----
// bid&7 = XCD -> m-band of 8 tiles (A-band 2 MB, L2-resident); mi-inner, n-outer.
template <bool OUT_BF16>
__global__ __launch_bounds__(256) void gemm_bt(const bf16* __restrict__ A,
                                               const bf16* __restrict__ Bt,
                                               const float* __restrict__ bias,
                                               void* __restrict__ Cptr,
                                               int M, int N, int K) {
  __shared__ __align__(16) bf16 As[128 * 64];
  __shared__ __align__(16) bf16 Bs[128 * 64];
  const int tid  = threadIdx.x;
  const int lane = tid & 63, w = tid >> 6;
  const int lo   = lane & 15, quad = lane >> 4;
  const int xcd = blockIdx.x & 7, g = blockIdx.x >> 3;
  const int mi  = g & 7,          n = g >> 3;
  const int bm  = (xcd * 8 + mi) * 128, bn = n * 128;
  const int wm = (w >> 1) * 64,    wn = (w & 1) * 64;

  f32x4 acc[4][4];
  const f32x4 zero = {0.f, 0.f, 0.f, 0.f};
#pragma unroll
  for (int i = 0; i < 4; ++i)
#pragma unroll
    for (int j = 0; j < 4; ++j) acc[i][j] = zero;

  for (int k0 = 0; k0 < K; k0 += 64) {
#pragma unroll
    for (int c = 0; c < 4; ++c) {
      int seg = c * 4 + w;
      int idx = seg * 512 + lane * 8;
      int row = idx >> 6, col = idx & 63;
      gl2lds16(A  + (size_t)(bm + row) * K + k0 + col, As + seg * 512);
      gl2lds16(Bt + (size_t)(bn + row) * K + k0 + col, Bs + seg * 512);
    }
    __syncthreads();
#pragma unroll
    for (int ks = 0; ks < 2; ++ks) {
      bf16x8 av[4], bv[4];
#pragma unroll
      for (int i = 0; i < 4; ++i)
        av[i] = *(const bf16x8*)&As[(wm + i * 16 + lo) * 64 + ks * 32 + quad * 8];
#pragma unroll
      for (int j = 0; j < 4; ++j)
        bv[j] = *(const bf16x8*)&Bs[(wn + j * 16 + lo) * 64 + ks * 32 + quad * 8];
#pragma unroll
      for (int i = 0; i < 4; ++i)
#pragma unroll
        for (int j = 0; j < 4; ++j)
          acc[i][j] = __builtin_amdgcn_mfma_f32_16x16x32_bf16(av[i], bv[j], acc[i][j], 0, 0, 0);
    }
    __syncthreads();
  }
#pragma unroll
  for (int j = 0; j < 4; ++j) {
    int cg = bn + wn + j * 16 + lo;
    float bsv = bias[cg];
#pragma unroll
    for (int i = 0; i < 4; ++i) {
      int rg = bm + wm + i * 16 + quad * 4;
#pragma unroll
      for (int r = 0; r < 4; ++r) {
        float v = acc[i][j][r] + bsv;
        if (OUT_BF16) ((bf16*)Cptr)[(size_t)(rg + r) * N + cg] = (bf16)v;
        else          ((float*)Cptr)[(size_t)(rg + r) * N + cg] = v;
      }
    }
  }
}

// ---- 128x256 GEMM (qkv): doubles MFMA per barrier to amortize the per-iter
// vmcnt(0)+barrier drain at K=1024 (16 iters). Waves 2x2: each 64m x 128n,
// 4x8 16x16x32 MFMAs, 128 AGPR acc -> launch_bounds(256,2).
__global__ __launch_bounds__(256, 2) void gemm_bt_wide(const bf16* __restrict__ A,
                                                       const bf16* __restrict__ Bt,
                                                       const float* __restrict__ bias,
                                                       bf16* __restrict__ Cptr,
                                                       int M, int N, int K) {
  __shared__ __align__(16) bf16 As[128 * 64];   // 16 KB
  __shared__ __align__(16) bf16 Bs[256 * 64];   // 32 KB
  const int tid  = threadIdx.x;
  const int lane = tid & 63, w = tid >> 6;
  const int lo   = lane & 15, quad = lane >> 4;
  const int xcd = blockIdx.x & 7, g = blockIdx.x >> 3;
  const int mi  = g & 7,          n = g >> 3;
  const int bm  = (xcd * 8 + mi) * 128, bn = n * 256;
  const int wm = (w >> 1) * 64,    wn = (w & 1) * 128;

  f32x4 acc[4][8];
  const f32x4 zero = {0.f, 0.f, 0.f, 0.f};
#pragma unroll
  for (int i = 0; i < 4; ++i)
#pragma unroll
    for (int j = 0; j < 8; ++j) acc[i][j] = zero;

  for (int k0 = 0; k0 < K; k0 += 64) {
#pragma unroll
    for (int c = 0; c < 4; ++c) {
      int seg = c * 4 + w;
      int idx = seg * 512 + lane * 8;
      int row = idx >> 6, col = idx & 63;
      gl2lds16(A + (size_t)(bm + row) * K + k0 + col, As + seg * 512);
    }
#pragma unroll
    for (int c = 0; c < 8; ++c) {
      int seg = c * 4 + w;
      int idx = seg * 512 + lane * 8;
      int row = idx >> 6, col = idx & 63;
      gl2lds16(Bt + (size_t)(bn + row) * K + k0 + col, Bs + seg * 512);
    }
    __syncthreads();
#pragma unroll
    for (int ks = 0; ks < 2; ++ks) {
      bf16x8 av[4], bv[8];
#pragma unroll
      for (int i = 0; i < 4; ++i)
        av[i] = *(const bf16x8*)&As[(wm + i * 16 + lo) * 64 + ks * 32 + quad * 8];
#pragma unroll
      for (int j = 0; j < 8; ++j)
        bv[j] = *(const bf16x8*)&Bs[(wn + j * 16 + lo) * 64 + ks * 32 + quad * 8];
#pragma unroll
      for (int i = 0; i < 4; ++i)
#pragma unroll
        for (int j = 0; j < 8; ++j)
          acc[i][j] = __builtin_amdgcn_mfma_f32_16x16x32_bf16(av[i], bv[j], acc[i][j], 0, 0, 0);
    }
    __syncthreads();
  }
#pragma unroll
  for (int j = 0; j < 8; ++j) {
    int cg = bn + wn + j * 16 + lo;
    float bsv = bias[cg];
#pragma unroll
    for (int i = 0; i < 4; ++i) {
      int rg = bm + wm + i * 16 + quad * 4;
#pragma unroll
      for (int r = 0; r < 4; ++r)
        Cptr[(size_t)(rg + r) * N + cg] = (bf16)(acc[i][j][r] + bsv);
    }
  }
}

// ---- flash attention v8 ----
// 128 q/block, 4 waves x 32 q, 32x32x16 MFMA. S^T = K.Q^T, O^T = Vt.P (q = C-col =
// lane&31 -> softmax in-lane). Fixed exponent offset (p = 2^(s*c2-16)). K staged via
// global_load_lds DMA one tile ahead, 16B-chunk XOR (s&7) permutation. V register-
// transposed into LDS with chunk-XOR-((d>>1)&7) swizzle: writes land 2x-floor (free),
// b128 A-frag reads at bank floor (fixes the 1.07e7-conflict V-write hotspot of
// pad-72). LDS 32 KB total -> full 4 blocks/CU under launch_bounds(256,4).
// Epilogue: O -> LDS (same swizzle, reuses Vs) -> coalesced 16B global stores.
__global__ __launch_bounds__(256, 4) void flash_attn(const bf16* __restrict__ qkv,
                                                     bf16* __restrict__ out) {
  __shared__ __align__(16) bf16 Ks[2][64 * 64];    // 16 KB, chunk-swizzled rows
  __shared__ __align__(16) bf16 Vs[2][64 * 64];    // 16 KB, [d][s] chunk-swizzled

  const int tid  = threadIdx.x;
  const int lane = tid & 63, wq = tid >> 6;
  const int l31  = lane & 31;
  const int e    = lane >> 5;           // hi1
  const int hi8  = e * 8, hi4 = e * 4;

  const int bid = blockIdx.x;
  const int qb  = bid >> 6;             // 0..15
  const int bh  = bid & 63;
  const int h   = bh & 15;
  const int b   = bh >> 4;
  const int q0  = qb * 128;
  const size_t rowb = (size_t)b * S_;
  const bf16* qbase = qkv + rowb * NQKV + h * HD_;
  const bf16* kbase = qbase + D_;
  const bf16* vbase = qbase + 2 * D_;

  // ---- Q fragments straight from global (loop-invariant) ----
  bf16x8 qf[4];
  {
    const bf16* qrow = qbase + (size_t)(q0 + wq * 32 + l31) * NQKV;
#pragma unroll
    for (int c = 0; c < 4; ++c)
      qf[c] = *(const bf16x8*)(qrow + c * 16 + hi8);
  }

  // ---- K DMA indices: chunk ci = it*256+tid -> global (s, x), LDS contiguous ----
  int kq_off[2];
#pragma unroll
  for (int it = 0; it < 2; ++it) {
    int ci = it * 256 + tid;
    int s  = ci >> 3;
    int x  = (ci & 7) ^ (s & 7);
    kq_off[it] = s * NQKV + x * 8;
  }
  // ---- V staging indices ----
  int vs_d[2], vs_s[2], vs_off[2];
#pragma unroll
  for (int u = 0; u < 2; ++u) {
    int idx = u * 256 + tid;
    int d0 = (idx & 31) * 2;
    int s0 = (idx >> 5) * 4;
    vs_d[u] = d0;
    vs_s[u] = s0;
    // LDS elem offset of the lane's 4-s run in row d0 (chunk-XOR swizzle)
    vs_off[u] = (((s0 >> 3) ^ ((d0 >> 1) & 7)) * 8) + (s0 & 7);
  }

  uint32_t vreg[2][4];

  // ---- prologue: DMA K tile 0 into buf0; prefetch V tile 0 regs ----
#pragma unroll
  for (int it = 0; it < 2; ++it)
    gl2lds16(kbase + kq_off[it], &Ks[0][(it * 256 + wq * 64) * 8]);
#pragma unroll
  for (int u = 0; u < 2; ++u)
#pragma unroll
    for (int j = 0; j < 4; ++j)
      vreg[u][j] = *(const uint32_t*)(vbase + (size_t)(vs_s[u] + j) * NQKV + vs_d[u]);

  const f32x16 zero16 = {0.f,0.f,0.f,0.f,0.f,0.f,0.f,0.f,0.f,0.f,0.f,0.f,0.f,0.f,0.f,0.f};
  f32x16 oacc[2];
  oacc[0] = zero16; oacc[1] = zero16;
  float lsum = 0.f;
  const float c2 = 0.125f * 1.44269504088896341f;   // scale * log2(e)

  for (int kt = 0; kt < 32; ++kt) {
    const int buf = kt & 1;
    // ---- write staged V regs to LDS (swizzled transpose) ----
#pragma unroll
    for (int u = 0; u < 2; ++u) {
      int d0 = vs_d[u];
      u16x4 lo, hi;
#pragma unroll
      for (int j = 0; j < 4; ++j) {
        lo[j] = (unsigned short)(vreg[u][j] & 0xffffu);
        hi[j] = (unsigned short)(vreg[u][j] >> 16);
      }
      *(u16x4*)&Vs[buf][(d0 + 0) * 64 + vs_off[u]] = lo;
      *(u16x4*)&Vs[buf][(d0 + 1) * 64 + vs_off[u]] = hi;
    }
    __syncthreads();

    // ---- async K DMA for NEXT tile into buf^1 (drained by next barrier) ----
    {
      int ktn = (kt + 1 < 32) ? kt + 1 : 31;
      const bf16* kb = kbase + (size_t)ktn * 64 * NQKV;
#pragma unroll
      for (int it = 0; it < 2; ++it)
        gl2lds16(kb + kq_off[it], &Ks[buf ^ 1][(it * 256 + wq * 64) * 8]);
    }
    // ---- V register prefetch for next tile ----
    {
      int ktn = (kt + 1 < 32) ? kt + 1 : 31;
      const bf16* vb = vbase + (size_t)ktn * 64 * NQKV;
#pragma unroll
      for (int u = 0; u < 2; ++u)
#pragma unroll
        for (int j = 0; j < 4; ++j)
          vreg[u][j] = *(const uint32_t*)(vb + (size_t)(vs_s[u] + j) * NQKV + vs_d[u]);
    }

    // ---- S^T = K.Q^T : 2 independent chains [32k x 32q], XOR-swizzled reads ----
    f32x16 sacc[2];
#pragma unroll
    for (int kk = 0; kk < 2; ++kk) {
      sacc[kk] = zero16;
      int srow = kk * 32 + l31;
      int swz  = (srow & 7) * 8;
#pragma unroll
      for (int c = 0; c < 4; ++c) {
        bf16x8 kf = *(const bf16x8*)&Ks[buf][srow * 64 + ((c * 16 + hi8) ^ swz)];
        sacc[kk] = __builtin_amdgcn_mfma_f32_32x32x16_bf16(kf, qf[c], sacc[kk], 0, 0, 0);
      }
    }

    // ---- per 32k-half: exp2 -> pack -> relayout -> O-MFMAs ----
#pragma unroll
    for (int kk = 0; kk < 2; ++kk) {
      uint32_t Q8[8];
      float ps = 0.f;
#pragma unroll
      for (int i = 0; i < 8; ++i) {
        float p0 = __builtin_amdgcn_exp2f(sacc[kk][2 * i]     * c2 - 16.0f);
        float p1 = __builtin_amdgcn_exp2f(sacc[kk][2 * i + 1] * c2 - 16.0f);
        ps += p0 + p1;
        Q8[i] = pkbf16(p0, p1);
      }
      lsum += ps;
#pragma unroll
      for (int mh = 0; mh < 2; ++mh) {
        const int m = kk * 2 + mh, bq = mh * 4;
        uint32_t s0 = e ? Q8[bq]     : Q8[bq + 2];
        uint32_t s1 = e ? Q8[bq + 1] : Q8[bq + 3];
        uint32_t r0 = __shfl_xor(s0, 32);
        uint32_t r1 = __shfl_xor(s1, 32);
        u32x4 pd;
        pd[0] = e ? r0 : Q8[bq];
        pd[1] = e ? r1 : Q8[bq + 1];
        pd[2] = e ? Q8[bq + 2] : r0;
        pd[3] = e ? Q8[bq + 3] : r1;
        bf16x8 pf = __builtin_bit_cast(bf16x8, pd);
#pragma unroll
        for (int dt = 0; dt < 2; ++dt) {
          int drow = dt * 32 + l31;
          int swv  = (drow >> 1) & 7;
          bf16x8 vf = *(const bf16x8*)&Vs[buf][drow * 64 + (((m * 2 + e) ^ swv) * 8)];
          oacc[dt] = __builtin_amdgcn_mfma_f32_32x32x16_bf16(vf, pf, oacc[dt], 0, 0, 0);
        }
      }
    }
  }

  lsum += __shfl_xor(lsum, 32);

  // ---- epilogue: O^T/lsum -> LDS (chunk-swizzled, reuse Vs) -> 16B stores ----
  __syncthreads();                       // all Ks/Vs reads done; safe to reuse
  bf16* Os = (bf16*)Vs;                  // [128][64] bf16, chunk-XOR ((row>>1)&7)
  {
    float inv = 1.f / lsum;
    int ql = wq * 32 + l31;
    int swO = (ql >> 1) & 7;
#pragma unroll
    for (int dt = 0; dt < 2; ++dt) {
#pragma unroll
      for (int g = 0; g < 4; ++g) {
        bf16x4 ov;
#pragma unroll
        for (int jj = 0; jj < 4; ++jj) ov[jj] = (bf16)(oacc[dt][g * 4 + jj] * inv);
        *(bf16x4*)&Os[ql * 64 + (((dt * 4 + g) ^ swO) * 8) + hi4] = ov;
      }
    }
  }
  __syncthreads();
#pragma unroll
  for (int it = 0; it < 4; ++it) {
    int idx = it * 256 + tid;
    int row = idx >> 3, c8 = idx & 7;
    bf16x8 t = *(const bf16x8*)&Os[row * 64 + ((c8 ^ ((row >> 1) & 7)) * 8)];
    *(bf16x8*)&out[(rowb + q0 + row) * D_ + h * HD_ + c8 * 8] = t;
  }
}

extern "C" void kernel_launch(void* const* d_in, const int* in_sizes, int n_in,
                              void* d_out, int out_size, void* d_ws, size_t ws_size,
                              hipStream_t stream) {
  const float* x     = (const float*)d_in[0];
  const float* w_qkv = (const float*)d_in[1];
  const float* b_qkv = (const float*)d_in[2];
  const float* w_out = (const float*)d_in[3];
  const float* b_out = (const float*)d_in[4];
  float* out = (float*)d_out;

  char* ws = (char*)d_ws;
  bf16* xb    = (bf16*)(ws);                         // 16 MB
  bf16* wqkvT = (bf16*)(ws + (size_t)16777216);      //  6 MB
  bf16* woutT = (bf16*)(ws + (size_t)23068672);      //  2 MB
  bf16* qkvb  = (bf16*)(ws + (size_t)25165824);      // 48 MB
  bf16* attnb = (bf16*)(ws + (size_t)75497472);      // 16 MB

  cast_f32_bf16<<<(M_ * D_ / 4 + 255) / 256, 256, 0, stream>>>(x, xb, M_ * D_ / 4);
  transpose_cast<<<dim3(NQKV / 32, D_ / 32), dim3(32, 8), 0, stream>>>(w_qkv, wqkvT, D_, NQKV);
  transpose_cast<<<dim3(D_ / 32, D_ / 32), dim3(32, 8), 0, stream>>>(w_out, woutT, D_, D_);

  gemm_bt_wide<<<(M_ / 128) * (NQKV / 256), 256, 0, stream>>>(
      xb, wqkvT, b_qkv, qkvb, M_, NQKV, D_);

  flash_attn<<<B_ * H_ * (S_ / 128), 256, 0, stream>>>(qkvb, attnb);

  gemm_bt<false><<<(M_ / 128) * (D_ / 128), 256, 0, stream>>>(
      attnb, woutT, b_out, (void*)out, M_, D_, D_);
}